// Round 2
// baseline (174.246 us; speedup 1.0000x reference)
//
#include <hip/hip_runtime.h>
#include <hip/hip_bf16.h>

#define RS   100            // row stride (floats) of a 97x97 plane (padded for float4 alignment)
#define PLS  9700           // plane stride = 97 rows * RS
#define NP   9409           // 97*97 valid elements per plane

// ws layout (float offsets) — planes only; weights are read directly from d_in (fp32)
#define OFF_R  0                         // 4*32 planes (pooled relations, padded/shifted)
#define OFF_A  (OFF_R  + 4*32*PLS)       // 4*16 planes (ft projection)
#define OFF_Bm (OFF_A  + 4*16*PLS)       // 4*16 planes (rt projection)
#define OFF_F  (OFF_Bm + 4*16*PLS)       // 4*16 planes (dp output)
// total = 320 planes * 9700 * 4 B = 12.42 MB of ws

__device__ __forceinline__ float sigm(float x) { return 1.0f / (1.0f + __expf(-x)); }

// ---------------- interval pooling (max & min) + pad -> R planes ----------------
// One block per (b, ch); ch<16: max over channel ch, ch>=16: min over channel ch-16
// (min computed as -cummax(-x)). Output R[(b*32+ch)][x][y] = padded r, zeros outside.
__global__ __launch_bounds__(128) void pool_kernel(const float* __restrict__ a, float* __restrict__ R) {
    __shared__ float s[96][97];   // +1 pad breaks bank-conflict strides
    const int tid = threadIdx.x;
    const int b  = blockIdx.x >> 5;
    const int ch = blockIdx.x & 31;
    const int d  = ch & 15;
    const bool isMin = (ch >= 16);

    // load + mask (x = a where j>=i else -BIG), negate for min channels
    for (int idx = tid; idx < 96 * 96; idx += 128) {
        int i = idx / 96, j = idx - i * 96;
        float v = a[((size_t)(b * 96 + i) * 96 + j) * 16 + d];
        if (isMin) v = -v;
        s[i][j] = (j >= i) ? v : -1e30f;
    }
    __syncthreads();
    // reverse cummax over i (thread = column j)
    if (tid < 96) {
        int j = tid; float run = -1e30f;
        for (int i = 95; i >= 0; --i) { run = fmaxf(run, s[i][j]); s[i][j] = run; }
    }
    __syncthreads();
    // forward cummax over j (thread = row i)
    if (tid < 96) {
        int i = tid; float run = -1e30f;
        for (int j = 0; j < 96; ++j) { run = fmaxf(run, s[i][j]); s[i][j] = run; }
    }
    __syncthreads();
    // write padded plane: r[x][y] = pool[x][y-1] if (x<=95 && y>=1 && x<=y-1) else 0
    float* Rp = R + (size_t)blockIdx.x * PLS;
    for (int idx = tid; idx < 97 * 97; idx += 128) {
        int x = idx / 97, y = idx - x * 97;
        float v = 0.f;
        if (x <= 95 && y >= 1 && x <= y - 1) { v = s[x][y - 1]; if (isMin) v = -v; }
        Rp[x * RS + y] = v;
    }
}

// ---------------- projection step 0: A = r@Wf, B = r@Wr ----------------
// W = W0 (64x16 fp32): Wf = rows 0..31, Wr = rows 32..63
__global__ __launch_bounds__(256) void proj0_kernel(const float* __restrict__ R, const float* __restrict__ W,
                                                    float* __restrict__ A, float* __restrict__ B) {
    const int bh = blockIdx.y, b = bh >> 4, h = bh & 15;
    const int p = blockIdx.x * 256 + threadIdx.x;
    if (p >= NP) return;
    const int x = p / 97, y = p - x * 97;
    const int off = x * RS + y;
    const float* Rb = R + (size_t)b * 32 * PLS + off;
    float accA = 0.f, accB = 0.f;
#pragma unroll
    for (int d = 0; d < 32; ++d) {
        float rv = Rb[(size_t)d * PLS];
        accA += rv * W[d * 16 + h];
        accB += rv * W[(32 + d) * 16 + h];
    }
    A[(size_t)bh * PLS + off] = accA;
    B[(size_t)bh * PLS + off] = accB;
}

// ---------------- projection step 1: A = [f1,r]@Wf, B = r@Wr ----------------
// W = W1 (80x16 fp32): Wf = rows 0..47 (0..15 apply to f1, 16..47 to r), Wr = rows 48..79
__global__ __launch_bounds__(256) void proj1_kernel(const float* __restrict__ R, const float* __restrict__ F1,
                                                    const float* __restrict__ W,
                                                    float* __restrict__ A, float* __restrict__ B) {
    const int bh = blockIdx.y, b = bh >> 4, h = bh & 15;
    const int p = blockIdx.x * 256 + threadIdx.x;
    if (p >= NP) return;
    const int x = p / 97, y = p - x * 97;
    const int off = x * RS + y;
    const float* Rb = R  + (size_t)b * 32 * PLS + off;
    const float* Fb = F1 + (size_t)b * 16 * PLS + off;
    float accA = 0.f, accB = 0.f;
#pragma unroll
    for (int c = 0; c < 16; ++c) accA += Fb[(size_t)c * PLS] * W[c * 16 + h];
#pragma unroll
    for (int d = 0; d < 32; ++d) {
        float rv = Rb[(size_t)d * PLS];
        accA += rv * W[(16 + d) * 16 + h];
        accB += rv * W[(48 + d) * 16 + h];
    }
    A[(size_t)bh * PLS + off] = accA;
    B[(size_t)bh * PLS + off] = accB;
}

// ---------------- max-plus "GEMM": F[i][j] = sigmoid(bias + max_k A[i][k]+B[k][j]) ----------------
// sigmoid is monotonic => max_k sigmoid(.) = sigmoid(max_k .): one sigmoid per output.
// grid: (4 tiles of 2x2, 64 (b,h) planes); block 256 = 16x16 threads, 4x4 results each
__global__ __launch_bounds__(256) void maxplus_kernel(const float* __restrict__ A, const float* __restrict__ Bm,
                                                      const float* __restrict__ bias, float* __restrict__ F) {
    __shared__ alignas(16) float As[97][68];  // As[k][i-local] (transposed), stride 68: float4-aligned rows
    __shared__ alignas(16) float Bs[97][68];  // Bs[k][j-local]
    const int tid = threadIdx.x;
    const int bh = blockIdx.y;
    const int h  = bh & 15;
    const int i0 = (blockIdx.x & 1) * 64;
    const int j0 = (blockIdx.x >> 1) * 64;
    const float* Ab = A  + (size_t)bh * PLS;
    const float* Bb = Bm + (size_t)bh * PLS;

    for (int idx = tid; idx < 64 * 97; idx += 256) {      // transpose-stage A panel
        int r = idx / 97, k = idx - r * 97;
        int ii = i0 + r;
        As[k][r] = (ii < 97) ? Ab[ii * RS + k] : -1e30f;
    }
    for (int idx = tid; idx < 97 * 64; idx += 256) {      // direct-stage B panel
        int k = idx >> 6, c = idx & 63;
        int jj = j0 + c;
        Bs[k][c] = (jj < 97) ? Bb[k * RS + jj] : -1e30f;
    }
    __syncthreads();

    const int ty = tid >> 4, tx = tid & 15;
    float acc[4][4];
#pragma unroll
    for (int r = 0; r < 4; ++r)
#pragma unroll
        for (int c = 0; c < 4; ++c) acc[r][c] = -1e30f;

#pragma unroll 4
    for (int k = 0; k < 97; ++k) {
        const float4 a4 = *reinterpret_cast<const float4*>(&As[k][ty * 4]);
        const float4 b4 = *reinterpret_cast<const float4*>(&Bs[k][tx * 4]);
        const float ar[4] = {a4.x, a4.y, a4.z, a4.w};
        const float bc[4] = {b4.x, b4.y, b4.z, b4.w};
#pragma unroll
        for (int r = 0; r < 4; ++r)
#pragma unroll
            for (int c = 0; c < 4; ++c)
                acc[r][c] = fmaxf(acc[r][c], ar[r] + bc[c]);
    }

    const float bb = bias[h];
    float* Fb = F + (size_t)bh * PLS;
#pragma unroll
    for (int r = 0; r < 4; ++r) {
        const int row = i0 + ty * 4 + r;
        if (row > 96) continue;
        const int col0 = j0 + tx * 4;
        if (col0 + 3 <= 96) {
            float4 v;
            v.x = sigm(acc[r][0] + bb);
            v.y = sigm(acc[r][1] + bb);
            v.z = sigm(acc[r][2] + bb);
            v.w = sigm(acc[r][3] + bb);
            *reinterpret_cast<float4*>(&Fb[row * RS + col0]) = v;
        } else {
            for (int c = 0; c < 4; ++c) {
                const int col = col0 + c;
                if (col <= 96) Fb[row * RS + col] = sigm(acc[r][c] + bb);
            }
        }
    }
}

// ---------------- final: out = sigmoid([f2,r] @ W2 + b2), cropped [:, :-1, 1:] ----------------
__global__ __launch_bounds__(256) void final_kernel(const float* __restrict__ R, const float* __restrict__ F2,
                                                    const float* __restrict__ W, const float* __restrict__ bias,
                                                    float* __restrict__ out) {
    const int p = blockIdx.x * 256 + threadIdx.x;
    if (p >= 4 * 96 * 96) return;
    const int oj = p % 96;
    const int t1 = p / 96;
    const int i  = t1 % 96;
    const int b  = t1 / 96;
    const int off = i * RS + (oj + 1);   // j = oj+1 (crop)
    const float* Fb = F2 + (size_t)b * 16 * PLS + off;
    const float* Rb = R  + (size_t)b * 32 * PLS + off;
    float acc[16];
#pragma unroll
    for (int o = 0; o < 16; ++o) acc[o] = bias[o];
#pragma unroll
    for (int c = 0; c < 16; ++c) {
        const float fv = Fb[(size_t)c * PLS];
#pragma unroll
        for (int o = 0; o < 16; ++o) acc[o] += fv * W[c * 16 + o];
    }
#pragma unroll
    for (int d = 0; d < 32; ++d) {
        const float rv = Rb[(size_t)d * PLS];
#pragma unroll
        for (int o = 0; o < 16; ++o) acc[o] += rv * W[(16 + d) * 16 + o];
    }
    float4* dst = reinterpret_cast<float4*>(out + (size_t)p * 16);
#pragma unroll
    for (int q = 0; q < 4; ++q) {
        float4 v;
        v.x = sigm(acc[q * 4 + 0]);
        v.y = sigm(acc[q * 4 + 1]);
        v.z = sigm(acc[q * 4 + 2]);
        v.w = sigm(acc[q * 4 + 3]);
        dst[q] = v;
    }
}

extern "C" void kernel_launch(void* const* d_in, const int* in_sizes, int n_in,
                              void* d_out, int out_size, void* d_ws, size_t ws_size,
                              hipStream_t stream) {
    const float* a  = (const float*)d_in[0];
    const float* W0 = (const float*)d_in[1];
    const float* b0 = (const float*)d_in[2];
    const float* W1 = (const float*)d_in[3];
    const float* b1 = (const float*)d_in[4];
    const float* W2 = (const float*)d_in[5];
    const float* b2 = (const float*)d_in[6];
    float* ws = (float*)d_ws;
    float* out = (float*)d_out;

    hipLaunchKernelGGL(pool_kernel, dim3(128), dim3(128), 0, stream, a, ws + OFF_R);
    hipLaunchKernelGGL(proj0_kernel, dim3(37, 64), dim3(256), 0, stream,
                       ws + OFF_R, W0, ws + OFF_A, ws + OFF_Bm);
    hipLaunchKernelGGL(maxplus_kernel, dim3(4, 64), dim3(256), 0, stream,
                       ws + OFF_A, ws + OFF_Bm, b0, ws + OFF_F);
    hipLaunchKernelGGL(proj1_kernel, dim3(37, 64), dim3(256), 0, stream,
                       ws + OFF_R, ws + OFF_F, W1, ws + OFF_A, ws + OFF_Bm);
    hipLaunchKernelGGL(maxplus_kernel, dim3(4, 64), dim3(256), 0, stream,
                       ws + OFF_A, ws + OFF_Bm, b1, ws + OFF_F);
    hipLaunchKernelGGL(final_kernel, dim3(144), dim3(256), 0, stream,
                       ws + OFF_R, ws + OFF_F, W2, b2, out);
}